// Round 1
// baseline (2080.391 us; speedup 1.0000x reference)
//
#include <hip/hip_runtime.h>
#include <cfloat>

// Problem constants: B=16, N=8192, C=256; M derived from out_size (=2048).
#define BB 16
#define NN 8192
#define CC 256
#define NT 512                  // threads per FPS block (8 waves)
#define PPT 16                  // points per thread
#define NPAIR (PPT / 2)         // 8 packed f32x2 pairs
#define NWAVES (NT / 64)        // 8
#define TBLOCKS 240             // transpose helper blocks (fill idle CUs)
#define NTILES (BB * (CC / 64) * (NN / 64))   // 16*4*128 = 8192 64x64 tiles
#define NCELL 512               // 8x8x8 Morton cells for the spatial sort

typedef float    v2f __attribute__((ext_vector_type(2)));
typedef unsigned v2u __attribute__((ext_vector_type(2)));
typedef unsigned uu;
typedef unsigned long long ull;

// lgkmcnt-only barrier: our only cross-wave data in the main loop is the LDS
// key write; do NOT drain vmcnt (wave 0's per-iter global stores).
#define LDS_BARRIER() __asm__ __volatile__("s_waitcnt lgkmcnt(0)\n\ts_barrier" ::: "memory")

// ---- Shared memory ----
// R5: big aliased region. Timeline within one FPS block:
//   phase A (setup): SmemSort — Morton counting-sort scratch (132 KB)
//   phase B (loop):  SmemFPS  — coord mirror in ORIGINAL index order (96 KB),
//                    written from registers AFTER the sorted reload (barrier-
//                    separated, so aliasing sx/sy/sz is safe).
// Transpose path uses SmemT. Control data (keys/reductions) lives outside the
// union so it never aliases.
struct SmemSort {
  float sx[NN], sy[NN], sz[NN];   // Morton-sorted coords
  uu    sidx[NN];                 // ~orig_index per sorted slot
  uu    hist[NCELL], cur[NCELL];
};
struct SmemFPS { float px[NN], py[NN], pz[NN]; };
struct SmemT { float tile[64][65]; };               // padded transpose tile
union SmemBig { SmemSort s; SmemFPS f; SmemT t; };  // 135168 B
struct SmemCtl {
  ull   key[2][NWAVES];           // double-buffered wave keys
  float red[NWAVES][9];           // centroid sum xyz + min xyz + max xyz
  float ctr[9];                   // cx,cy,cz, lox,loy,loz, hix,hiy,hiz
};

// ---- guaranteed-packed f32 math (VOP3P). Each half is a plain IEEE f32 op
// (round-to-nearest-even), bit-identical to the scalar version. ----
__device__ __forceinline__ v2f pk_sub(v2f a, v2f b) {
  v2f d;
  asm("v_pk_add_f32 %0, %1, %2 neg_lo:[0,1] neg_hi:[0,1]"
      : "=v"(d) : "v"(a), "v"(b));
  return d;
}
__device__ __forceinline__ v2f pk_mul(v2f a, v2f b) {
  v2f d;
  asm("v_pk_mul_f32 %0, %1, %2" : "=v"(d) : "v"(a), "v"(b));
  return d;
}
__device__ __forceinline__ v2f pk_add(v2f a, v2f b) {
  v2f d;
  asm("v_pk_add_f32 %0, %1, %2" : "=v"(d) : "v"(a), "v"(b));
  return d;
}

__device__ __forceinline__ uu umin2(uu a, uu b) { return a < b ? a : b; }
__device__ __forceinline__ uu umax2(uu a, uu b) { return a > b ? a : b; }

// key = (dist_bits << 32) | ~index. dist >= 0 -> u32 bit order == f32 order.
// max key = max dist; tie -> larger ~idx = smaller idx = numpy first-occurrence.
__device__ __forceinline__ ull max64(ull a, ull b) { return a > b ? a : b; }

template <int CTRL>
__device__ __forceinline__ ull dpp_max64(ull x) {
  int lo = (int)(uu)x;
  int hi = (int)(uu)(x >> 32);
  int plo = __builtin_amdgcn_update_dpp(0, lo, CTRL, 0xF, 0xF, true);
  int phi = __builtin_amdgcn_update_dpp(0, hi, CTRL, 0xF, 0xF, true);
  ull p = ((ull)(uu)phi << 32) | (uu)plo;
  return max64(x, p);
}

// Wave64 max funneled into lane 63, all on the VALU pipe (no LDS-pipe ops).
__device__ __forceinline__ ull wave_max63(ull k) {
  k = dpp_max64<0xB1>(k);    // quad_perm xor1
  k = dpp_max64<0x4E>(k);    // quad_perm xor2
  k = dpp_max64<0x124>(k);   // row_ror:4
  k = dpp_max64<0x128>(k);   // row_ror:8 -> full 16-lane row max
  k = dpp_max64<0x142>(k);   // row_bcast15
  k = dpp_max64<0x143>(k);   // row_bcast31 -> lane 63 has wave max
  return k;
}

// spread 3 bits to bit positions 0,3,6 (Morton interleave helper)
__device__ __forceinline__ uu sp3(int b) {
  uu u = (uu)b;
  return (u & 1u) | ((u & 2u) << 2) | ((u & 4u) << 4);
}

// blockIdx < BB: one FPS workgroup per batch.
// blockIdx >= BB (when do_trans): grid-stride transpose of features
// [B][C][N] -> trans [B][N][C], hidden under FPS on the idle 240 CUs.
__global__ __launch_bounds__(NT)
void fps_fused_kernel(const float* __restrict__ pts,
                      const float* __restrict__ feats,
                      float* __restrict__ out_pts,
                      int* __restrict__ idx_out,
                      float* __restrict__ trans, int M, int do_trans) {
  __shared__ SmemBig smb;
  __shared__ SmemCtl smc;
  const int t = threadIdx.x;

  if (blockIdx.x >= BB) {
    // ---------------- transpose path (unchanged) ----------------
    if (!do_trans) return;
    for (int tileId = blockIdx.x - BB; tileId < NTILES; tileId += TBLOCKS) {
      int b  = tileId / ((CC / 64) * (NN / 64));
      int r  = tileId % ((CC / 64) * (NN / 64));
      int ct = r / (NN / 64);
      int nt = r % (NN / 64);
      const float* src = feats + ((size_t)b * CC + ct * 64) * NN + nt * 64;
      float* dst = trans + ((size_t)b * NN + nt * 64) * CC + ct * 64;
#pragma unroll
      for (int i = 0; i < 2; ++i) {
        int f = t + i * NT;
        int c = f >> 4, n4 = f & 15;
        float4 v = *(const float4*)(src + (size_t)c * NN + n4 * 4);
        smb.t.tile[c][n4 * 4 + 0] = v.x;
        smb.t.tile[c][n4 * 4 + 1] = v.y;
        smb.t.tile[c][n4 * 4 + 2] = v.z;
        smb.t.tile[c][n4 * 4 + 3] = v.w;
      }
      __syncthreads();
#pragma unroll
      for (int i = 0; i < 2; ++i) {
        int f = t + i * NT;
        int n = f >> 4, c4 = f & 15;
        float4 o;
        o.x = smb.t.tile[c4 * 4 + 0][n];
        o.y = smb.t.tile[c4 * 4 + 1][n];
        o.z = smb.t.tile[c4 * 4 + 2][n];
        o.w = smb.t.tile[c4 * 4 + 3][n];
        *(float4*)(dst + (size_t)n * CC + c4 * 4) = o;
      }
      __syncthreads();
    }
    return;
  }

  // ---------------- FPS path ----------------
  const int b = blockIdx.x;
  const int wave = t >> 6;
  const int lane = t & 63;
  const float* base = pts + (size_t)b * 3 * NN;   // [3][N] for this batch

  // ---- load 16 pts/thread, original order, coalesced ----
  v2f px2[NPAIR], py2[NPAIR], pz2[NPAIR];
#pragma unroll
  for (int j = 0; j < NPAIR; ++j) {
    int n0 = t + (2 * j) * NT;
    int n1 = t + (2 * j + 1) * NT;
    px2[j] = (v2f){base[n0], base[NN + n0] * 0.f + base[n0] * 0.f + base[n0]}; // placeholder avoided below
    // (rewritten plainly:)
    float x0 = base[n0], y0 = base[NN + n0], z0 = base[2 * NN + n0];
    float x1 = base[n1], y1 = base[NN + n1], z1 = base[2 * NN + n1];
    px2[j] = (v2f){x0, x1};
    py2[j] = (v2f){y0, y1};
    pz2[j] = (v2f){z0, z1};
  }

  // ---- centroid (EXACT same summation order as previous kernel) + bbox ----
  float sx = 0.f, sy = 0.f, sz = 0.f;
  float mnx = FLT_MAX, mny = FLT_MAX, mnz = FLT_MAX;
  float mxx = -FLT_MAX, mxy = -FLT_MAX, mxz = -FLT_MAX;
#pragma unroll
  for (int j = 0; j < NPAIR; ++j) {
    sx += px2[j].x; sx += px2[j].y;
    sy += py2[j].x; sy += py2[j].y;
    sz += pz2[j].x; sz += pz2[j].y;
    mnx = fminf(mnx, fminf(px2[j].x, px2[j].y));
    mny = fminf(mny, fminf(py2[j].x, py2[j].y));
    mnz = fminf(mnz, fminf(pz2[j].x, pz2[j].y));
    mxx = fmaxf(mxx, fmaxf(px2[j].x, px2[j].y));
    mxy = fmaxf(mxy, fmaxf(py2[j].x, py2[j].y));
    mxz = fmaxf(mxz, fmaxf(pz2[j].x, pz2[j].y));
  }
#pragma unroll
  for (int off = 32; off > 0; off >>= 1) {
    sx += __shfl_xor(sx, off);
    sy += __shfl_xor(sy, off);
    sz += __shfl_xor(sz, off);
    mnx = fminf(mnx, __shfl_xor(mnx, off));
    mny = fminf(mny, __shfl_xor(mny, off));
    mnz = fminf(mnz, __shfl_xor(mnz, off));
    mxx = fmaxf(mxx, __shfl_xor(mxx, off));
    mxy = fmaxf(mxy, __shfl_xor(mxy, off));
    mxz = fmaxf(mxz, __shfl_xor(mxz, off));
  }
  if (lane == 0) {
    smc.red[wave][0] = sx;  smc.red[wave][1] = sy;  smc.red[wave][2] = sz;
    smc.red[wave][3] = mnx; smc.red[wave][4] = mny; smc.red[wave][5] = mnz;
    smc.red[wave][6] = mxx; smc.red[wave][7] = mxy; smc.red[wave][8] = mxz;
  }
  // zero the Morton histogram while reductions land (barrier below covers both)
  if (t < NCELL) smb.s.hist[t] = 0u;
  __syncthreads();
  if (t == 0) {
    float gx = 0.f, gy = 0.f, gz = 0.f;
    float lx = FLT_MAX, ly = FLT_MAX, lz = FLT_MAX;
    float hx = -FLT_MAX, hy = -FLT_MAX, hz = -FLT_MAX;
    for (int w = 0; w < NWAVES; ++w) {
      gx += smc.red[w][0]; gy += smc.red[w][1]; gz += smc.red[w][2];
      lx = fminf(lx, smc.red[w][3]); ly = fminf(ly, smc.red[w][4]); lz = fminf(lz, smc.red[w][5]);
      hx = fmaxf(hx, smc.red[w][6]); hy = fmaxf(hy, smc.red[w][7]); hz = fmaxf(hz, smc.red[w][8]);
    }
    smc.ctr[0] = gx / NN; smc.ctr[1] = gy / NN; smc.ctr[2] = gz / NN;  // /8192 exact
    smc.ctr[3] = lx; smc.ctr[4] = ly; smc.ctr[5] = lz;
    smc.ctr[6] = hx; smc.ctr[7] = hy; smc.ctr[8] = hz;
  }
  __syncthreads();
  const float ctx = smc.ctr[0], cty = smc.ctr[1], ctz = smc.ctr[2];
  const float lox = smc.ctr[3], loy = smc.ctr[4], loz = smc.ctr[5];
  const float wxs = smc.ctr[6] - lox, wys = smc.ctr[7] - loy, wzs = smc.ctr[8] - loz;
  const float sclx = wxs > 0.f ? 8.0f / wxs : 0.f;
  const float scly = wys > 0.f ? 8.0f / wys : 0.f;
  const float sclz = wzs > 0.f ? 8.0f / wzs : 0.f;

  // ---- Morton cell codes + LDS histogram (one-time) ----
  uu code[PPT];
#pragma unroll
  for (int k = 0; k < PPT; ++k) {
    float x = (k & 1) ? px2[k >> 1].y : px2[k >> 1].x;
    float y = (k & 1) ? py2[k >> 1].y : py2[k >> 1].x;
    float z = (k & 1) ? pz2[k >> 1].y : pz2[k >> 1].x;
    float fx = (x - lox) * sclx; fx = fx > 7.f ? 7.f : (fx < 0.f ? 0.f : fx);
    float fy = (y - loy) * scly; fy = fy > 7.f ? 7.f : (fy < 0.f ? 0.f : fy);
    float fz = (z - loz) * sclz; fz = fz > 7.f ? 7.f : (fz < 0.f ? 0.f : fz);
    code[k] = sp3((int)fx) | (sp3((int)fy) << 1) | (sp3((int)fz) << 2);
    atomicAdd(&smb.s.hist[code[k]], 1u);
  }
  __syncthreads();

  // ---- exclusive prefix sum over 512 bins (wave 0) ----
  if (wave == 0) {
    uu h[8]; uu s = 0u;
#pragma unroll
    for (int j2 = 0; j2 < 8; ++j2) { h[j2] = smb.s.hist[lane * 8 + j2]; s += h[j2]; }
    uu inc = s;
#pragma unroll
    for (int d = 1; d < 64; d <<= 1) { uu tt = __shfl_up(inc, d); if (lane >= d) inc += tt; }
    uu run = inc - s;                  // exclusive across lanes
#pragma unroll
    for (int j2 = 0; j2 < 8; ++j2) { smb.s.cur[lane * 8 + j2] = run; run += h[j2]; }
  }
  __syncthreads();

  // ---- scatter into Morton order (position via LDS atomic; any intra-cell
  // order is fine: keys carry the ORIGINAL index so the result is exactly
  // permutation-invariant) ----
#pragma unroll
  for (int k = 0; k < PPT; ++k) {
    float x = (k & 1) ? px2[k >> 1].y : px2[k >> 1].x;
    float y = (k & 1) ? py2[k >> 1].y : py2[k >> 1].x;
    float z = (k & 1) ? pz2[k >> 1].y : pz2[k >> 1].x;
    uu p = atomicAdd(&smb.s.cur[code[k]], 1u);
    smb.s.sx[p] = x; smb.s.sy[p] = y; smb.s.sz[p] = z;
    smb.s.sidx[p] = ~(uu)(t + k * NT);
  }
  __syncthreads();

  // ---- reload: thread owns 16 CONSECUTIVE sorted points (spatially compact)
  v2u dist2[NPAIR];
  uu nidx[PPT];
  const uu INIT = __float_as_uint(1e10f);   // matches jnp.full(1e10)
  const int base16 = t * PPT;
#pragma unroll
  for (int j = 0; j < NPAIR; ++j) {
    int p0 = base16 + 2 * j, p1 = p0 + 1;
    px2[j] = (v2f){smb.s.sx[p0], smb.s.sx[p1]};
    py2[j] = (v2f){smb.s.sy[p0], smb.s.sy[p1]};
    pz2[j] = (v2f){smb.s.sz[p0], smb.s.sz[p1]};
    nidx[2 * j] = smb.s.sidx[p0];
    nidx[2 * j + 1] = smb.s.sidx[p1];
    dist2[j] = (v2u){INIT, INIT};
  }
  // thread-group bbox (exact f32 min/max of member coords -> true bounds)
  float bxlo = FLT_MAX, bylo = FLT_MAX, bzlo = FLT_MAX;
  float bxhi = -FLT_MAX, byhi = -FLT_MAX, bzhi = -FLT_MAX;
#pragma unroll
  for (int j = 0; j < NPAIR; ++j) {
    bxlo = fminf(bxlo, fminf(px2[j].x, px2[j].y));
    bylo = fminf(bylo, fminf(py2[j].x, py2[j].y));
    bzlo = fminf(bzlo, fminf(pz2[j].x, pz2[j].y));
    bxhi = fmaxf(bxhi, fmaxf(px2[j].x, px2[j].y));
    byhi = fmaxf(byhi, fmaxf(py2[j].x, py2[j].y));
    bzhi = fmaxf(bzhi, fmaxf(pz2[j].x, pz2[j].y));
  }
  // cached key: exact argmax key over this thread's CURRENT dist[] values.
  // All dist == 1e10 now -> (INIT, max ~idx) is the exact key; also forces a
  // full update at m=0 (lb2 can never reach 1e10 on real data).
  uu myv = INIT, myc = 0u;
#pragma unroll
  for (int k = 0; k < PPT; ++k) myc = umax2(myc, nidx[k]);
  __syncthreads();                     // all sort-region reads done

  // ---- rebuild coord mirror in ORIGINAL index order (aliases sort region —
  // safe: barrier-separated; every point written exactly once) ----
#pragma unroll
  for (int k = 0; k < PPT; ++k) {
    uu o = ~nidx[k];
    float x = (k & 1) ? px2[k >> 1].y : px2[k >> 1].x;
    float y = (k & 1) ? py2[k >> 1].y : py2[k >> 1].x;
    float z = (k & 1) ? pz2[k >> 1].y : pz2[k >> 1].x;
    smb.f.px[o] = x; smb.f.py[o] = y; smb.f.pz[o] = z;
  }
  __syncthreads();

  int ep = 0;   // key epoch (parity double-buffer -> one barrier per iter)
  int ci;

  // Tail: u64 key wave reduce via DPP (VALU only), lane-63 write, ONE
  // lgkm-only barrier, then a spread b64 read + 3 DPP steps. Unchanged from
  // the proven kernel except the key's low word is now the thread's cached
  // ~orig_idx (computed in the update path) instead of a linear-layout index.
  auto reduce_tail = [&](uu v, uu c) {
    ull key = ((ull)v << 32) | c;
    key = wave_max63(key);
    ep ^= 1;
    if (lane == 63) smc.key[ep][wave] = key;
    LDS_BARRIER();                     // lgkmcnt-only: no global-store drain
    ull kk = smc.key[ep][lane & 7];    // spread ds_read_b64
    kk = dpp_max64<0xB1>(kk);
    kk = dpp_max64<0x4E>(kk);
    kk = dpp_max64<0x124>(kk);
    ci = (int)~(uu)kk;
  };

  // ---- initial farthest = argmax of dist-to-centroid (no dist update) ----
  {
    v2f c2x = {ctx, ctx}, c2y = {cty, cty}, c2z = {ctz, ctz};
    v2u nd2[NPAIR];
    uu v = 0u;
#pragma unroll
    for (int j = 0; j < NPAIR; ++j) {
      v2f dx = pk_sub(px2[j], c2x);
      v2f dy = pk_sub(py2[j], c2y);
      v2f dz = pk_sub(pz2[j], c2z);
      // exact numpy order: ((dx*dx + dy*dy) + dz*dz), no FMA
      v2f d = pk_add(pk_add(pk_mul(dx, dx), pk_mul(dy, dy)), pk_mul(dz, dz));
      v2u du = (v2u){__float_as_uint(d.x), __float_as_uint(d.y)};
      nd2[j] = du;
      v = umax2(v, umax2(du.x, du.y));           // v_max3_u32
    }
    uu c = 0u;
#pragma unroll
    for (int j = 0; j < NPAIR; ++j) {            // ties -> max ~idx = min idx
      c = umax2(c, nd2[j].x == v ? nidx[2 * j] : 0u);
      c = umax2(c, nd2[j].y == v ? nidx[2 * j + 1] : 0u);
    }
    reduce_tail(v, c);
  }

  // ---- FPS main loop with exact bbox pruning ----
  // Skip rule: if lb2*(1-1e-6) >= max(dist in group) then for every member
  // computed_d >= stored dist (rel. rounding of both sides < 6e-7), so
  // min(dist,d)==dist bit-exactly and the cached key stays valid.
  for (int m = 0; m < M; ++m) {
    // winner coords: 3x b32 same-address broadcast (conflict-free)
    float cx = smb.f.px[ci], cy = smb.f.py[ci], cz = smb.f.pz[ci];
    if (t == 0) {
      idx_out[b * M + m] = ci;
      size_t o = ((size_t)b * M + m) * 3;
      out_pts[o] = cx; out_pts[o + 1] = cy; out_pts[o + 2] = cz;
    }
    if (m == M - 1) break;

    float dxx = fmaxf(fmaxf(bxlo - cx, cx - bxhi), 0.f);   // v_max3_f32
    float dyy = fmaxf(fmaxf(bylo - cy, cy - byhi), 0.f);
    float dzz = fmaxf(fmaxf(bzlo - cz, cz - bzhi), 0.f);
    float lb2 = (dxx * dxx + dyy * dyy) + dzz * dzz;
    bool need = (lb2 * 0.999999f) < __uint_as_float(myv);

    if (need) {
      v2f c2x = {cx, cx}, c2y = {cy, cy}, c2z = {cz, cz};
      v2u nd2[NPAIR];
      uu v = 0u;
#pragma unroll
      for (int j = 0; j < NPAIR; ++j) {
        v2f dx = pk_sub(px2[j], c2x);
        v2f dy = pk_sub(py2[j], c2y);
        v2f dz = pk_sub(pz2[j], c2z);
        v2f d = pk_add(pk_add(pk_mul(dx, dx), pk_mul(dy, dy)), pk_mul(dz, dz));
        // dists >= 0 -> u32 min/max on the bits == f32 min/max
        v2u nd;
        nd.x = umin2(dist2[j].x, __float_as_uint(d.x));
        nd.y = umin2(dist2[j].y, __float_as_uint(d.y));
        dist2[j] = nd;
        nd2[j] = nd;
        v = umax2(v, umax2(nd.x, nd.y));         // v_max3_u32 chain
      }
      uu c = 0u;
#pragma unroll
      for (int j = 0; j < NPAIR; ++j) {
        c = umax2(c, nd2[j].x == v ? nidx[2 * j] : 0u);
        c = umax2(c, nd2[j].y == v ? nidx[2 * j + 1] : 0u);
      }
      myv = v; myc = c;
    }
    reduce_tail(myv, myc);
  }
}

// Gather from transposed features: fully coalesced float4 both sides.
__global__ __launch_bounds__(256)
void gather_t_kernel(const float* __restrict__ trans,
                     const int* __restrict__ idx,
                     float* __restrict__ out_f, int M) {
  int gm = blockIdx.x * 4 + (threadIdx.x >> 6);
  if (gm >= BB * M) return;
  int lane = threadIdx.x & 63;
  int b = gm / M;
  int n = idx[gm];
  float4 v = *(const float4*)(trans + ((size_t)b * NN + n) * CC + lane * 4);
  *(float4*)(out_f + (size_t)gm * CC + lane * 4) = v;
}

// Fallback gather (ws too small for transpose): scattered reads, L2/L3-bound.
__global__ __launch_bounds__(CC)
void gather_kernel(const float* __restrict__ feats, const int* __restrict__ idx,
                   float* __restrict__ out_f, int M) {
  const int bm = blockIdx.x;
  const int b = bm / M;
  const int n = idx[bm];
  const int c = threadIdx.x;
  out_f[(size_t)bm * CC + c] = feats[((size_t)b * CC + c) * NN + n];
}

extern "C" void kernel_launch(void* const* d_in, const int* in_sizes, int n_in,
                              void* d_out, int out_size, void* d_ws, size_t ws_size,
                              hipStream_t stream) {
  const float* points = (const float*)d_in[0];   // [B,3,N] f32
  const float* feats  = (const float*)d_in[1];   // [B,C,N] f32
  int M = out_size / (BB * (3 + CC));            // = 2048
  if (M <= 0) M = 1;

  float* out_pts = (float*)d_out;                        // [B,M,3]
  float* out_f   = (float*)d_out + (size_t)BB * M * 3;   // [B,M,C]

  int* idx_ws = (int*)d_ws;                              // B*M ints
  size_t idx_bytes = (((size_t)BB * M * sizeof(int)) + 255) & ~(size_t)255;
  size_t trans_bytes = (size_t)BB * NN * CC * sizeof(float);   // 134.2 MB
  bool use_t = (ws_size >= idx_bytes + trans_bytes);
  float* trans = (float*)((char*)d_ws + idx_bytes);

  int grid = use_t ? (BB + TBLOCKS) : BB;
  fps_fused_kernel<<<dim3(grid), dim3(NT), 0, stream>>>(
      points, feats, out_pts, idx_ws, trans, M, use_t ? 1 : 0);

  if (use_t) {
    gather_t_kernel<<<dim3((BB * M + 3) / 4), dim3(256), 0, stream>>>(
        trans, idx_ws, out_f, M);
  } else {
    gather_kernel<<<dim3(BB * M), dim3(CC), 0, stream>>>(feats, idx_ws, out_f, M);
  }
}